// Round 1
// baseline (117.081 us; speedup 1.0000x reference)
//
#include <hip/hip_runtime.h>

#define BB 2048
#define DD 4096
#define PP 64
#define KK 64
#define EE 8
#define C2 128
#define NBLK (BB / 4)

typedef __attribute__((ext_vector_type(8))) short short8;
typedef __attribute__((ext_vector_type(4))) float floatx4;

__device__ inline unsigned pack2_trunc(float lo, float hi) { // 2 bf16 (truncate) in 1 u32
    unsigned ul = __builtin_bit_cast(unsigned, lo);
    unsigned uh = __builtin_bit_cast(unsigned, hi);
    return (uh & 0xFFFF0000u) | (ul >> 16);
}

// Fused kernel: one wave per row (4 rows/block, 512 blocks). Loss fully fused via
// block-level LDS reduce -> 16 atomicAdds/block -> last-block finalize (no 2nd dispatch).
//  - x loaded directly in MFMA A-layout; fp32 col-sum partials for router; trunc->bf16 A-frags
//  - router: 8 dots via 6-step shfl_xor butterflies, strict first-max argmax (np semantics)
//  - selected expert's fp32 weights loaded from global (L2-resident), inline trunc->bf16 B-frags
//  - mfma 16x16x32 bf16, fused (z+bias)^3 epilogue -> 2 logits -> softmax
//  - ws[0..7]=sum_b select[b,e], ws[8..15]=argmax counts, ws[16]=done-counter (memset to 0 on stream)
__global__ __launch_bounds__(256) void moe_all(
    const float* __restrict__ x, const float* __restrict__ rw,
    const float* __restrict__ ew, const float* __restrict__ eb,
    float* __restrict__ out, float* __restrict__ ws)
{
    __shared__ float red[4][9];                          // per-wave d[0..7] + argmax
    const int lane = threadIdx.x & 63;
    const int w = threadIdx.x >> 6;
    const int b = blockIdx.x * 4 + w;                    // one row per wave
    const int r = lane & 15, q = lane >> 4;
    const float* xb = x + (size_t)b * DD;

    // ---- load x in MFMA A-layout; fp32 col-sum partials; pack bf16 A-frags
    float ps[16];
    #pragma unroll
    for (int j = 0; j < 16; ++j) ps[j] = 0.f;
    short8 af[8];                                        // [mt*2+kb]
    #pragma unroll
    for (int mt = 0; mt < 4; ++mt) {
        #pragma unroll
        for (int kb = 0; kb < 2; ++kb) {
            const float* base = xb + (mt * 16 + r) * 64 + kb * 32 + q * 8;
            float4 v0 = *(const float4*)base;
            float4 v1 = *(const float4*)(base + 4);
            ps[kb*8+0] += v0.x; ps[kb*8+1] += v0.y; ps[kb*8+2] += v0.z; ps[kb*8+3] += v0.w;
            ps[kb*8+4] += v1.x; ps[kb*8+5] += v1.y; ps[kb*8+6] += v1.z; ps[kb*8+7] += v1.w;
            uint4 u;
            u.x = pack2_trunc(v0.x, v0.y); u.y = pack2_trunc(v0.z, v0.w);
            u.z = pack2_trunc(v1.x, v1.y); u.w = pack2_trunc(v1.z, v1.w);
            af[mt * 2 + kb] = __builtin_bit_cast(short8, u);
        }
    }

    // ---- router (fp32; strict first-max argmax matches np)
    float d[8];
    #pragma unroll
    for (int e2 = 0; e2 < 8; ++e2) {
        const float* rwe = rw + e2 * KK;
        float4 a0 = *(const float4*)(rwe + q * 8);
        float4 a1 = *(const float4*)(rwe + q * 8 + 4);
        float4 b0 = *(const float4*)(rwe + 32 + q * 8);
        float4 b1 = *(const float4*)(rwe + 32 + q * 8 + 4);
        float t = ps[0]*a0.x + ps[1]*a0.y + ps[2]*a0.z + ps[3]*a0.w
                + ps[4]*a1.x + ps[5]*a1.y + ps[6]*a1.z + ps[7]*a1.w
                + ps[8]*b0.x + ps[9]*b0.y + ps[10]*b0.z + ps[11]*b0.w
                + ps[12]*b1.x + ps[13]*b1.y + ps[14]*b1.z + ps[15]*b1.w;
        t += __shfl_xor(t, 1);  t += __shfl_xor(t, 2);  t += __shfl_xor(t, 4);
        t += __shfl_xor(t, 8);  t += __shfl_xor(t, 16); t += __shfl_xor(t, 32);
        d[e2] = t;                                       // all lanes hold it
    }
    float gate = d[0]; int e = 0;
    #pragma unroll
    for (int e2 = 1; e2 < 8; ++e2)
        if (d[e2] > gate) { gate = d[e2]; e = e2; }

    if (lane == 0) {
        #pragma unroll
        for (int e2 = 0; e2 < 8; ++e2) red[w][e2] = d[e2];   // staged for in-block loss reduce
        red[w][8] = (float)e;
        float on = (gate != 0.f) ? 1.f : 0.f;
        float4 o0 = make_float4(e==0?on:0.f, e==1?on:0.f, e==2?on:0.f, e==3?on:0.f);
        float4 o1 = make_float4(e==4?on:0.f, e==5?on:0.f, e==6?on:0.f, e==7?on:0.f);
        *(float4*)(out + BB * 2 + b * 8)     = o0;       // select0
        *(float4*)(out + BB * 2 + b * 8 + 4) = o1;
    }

    // ---- expert compute: inline fp32->bf16 B-frags, mfma, fused (z+bias)^3
    const float* we = ew + (size_t)e * (C2 * KK);
    float h0 = 0.f, h1 = 0.f;
    #pragma unroll
    for (int nt = 0; nt < 8; ++nt) {
        float bs = eb[e * C2 + nt * 16 + r];             // c = nt*16 + (lane&15)
        const float* wr = we + (nt * 16 + r) * KK + q * 8;
        float4 w0 = *(const float4*)wr;
        float4 w1 = *(const float4*)(wr + 4);
        float4 w2 = *(const float4*)(wr + 32);
        float4 w3 = *(const float4*)(wr + 36);
        uint4 u0, u1;
        u0.x = pack2_trunc(w0.x, w0.y); u0.y = pack2_trunc(w0.z, w0.w);
        u0.z = pack2_trunc(w1.x, w1.y); u0.w = pack2_trunc(w1.z, w1.w);
        u1.x = pack2_trunc(w2.x, w2.y); u1.y = pack2_trunc(w2.z, w2.w);
        u1.z = pack2_trunc(w3.x, w3.y); u1.w = pack2_trunc(w3.z, w3.w);
        short8 bf0 = __builtin_bit_cast(short8, u0);
        short8 bf1 = __builtin_bit_cast(short8, u1);
        #pragma unroll
        for (int mt = 0; mt < 4; ++mt) {
            floatx4 a4 = (floatx4){0.f, 0.f, 0.f, 0.f};
            a4 = __builtin_amdgcn_mfma_f32_16x16x32_bf16(af[mt*2+0], bf0, a4, 0, 0, 0);
            a4 = __builtin_amdgcn_mfma_f32_16x16x32_bf16(af[mt*2+1], bf1, a4, 0, 0, 0);
            float hh = 0.f;
            #pragma unroll
            for (int i = 0; i < 4; ++i) {
                float z = a4[i] + bs;
                hh = fmaf(z * z, z, hh);
            }
            if (nt < 4) h0 += hh; else h1 += hh;
        }
    }
    #pragma unroll
    for (int off = 1; off < 64; off <<= 1) {
        h0 += __shfl_xor(h0, off);
        h1 += __shfl_xor(h1, off);
    }
    if (lane == 0) {
        float l0 = gate * h0, l1 = gate * h1;
        float m = fmaxf(l0, l1);
        float e0 = __expf(l0 - m), e1 = __expf(l1 - m);
        float inv = 1.f / (e0 + e1);
        float2 o; o.x = e0 * inv; o.y = e1 * inv;
        *(float2*)(out + b * 2) = o;
    }

    // ---- fused loss: block reduce (LDS) -> 16 atomicAdds -> last block finalizes
    __syncthreads();
    if (threadIdx.x < 8) {
        const int t = threadIdx.x;
        float sp = red[0][t] + red[1][t] + red[2][t] + red[3][t];
        float sc = 0.f;
        #pragma unroll
        for (int ww = 0; ww < 4; ++ww) sc += (red[ww][8] == (float)t) ? 1.f : 0.f;
        atomicAdd(ws + t, sp);
        atomicAdd(ws + 8 + t, sc);
    }
    __syncthreads();                                     // wave 0's atomics drained (vmcnt) at barrier
    if (threadIdx.x == 0) {
        __threadfence();
        unsigned old = __hip_atomic_fetch_add((unsigned*)(ws + 16), 1u,
                                              __ATOMIC_ACQ_REL, __HIP_MEMORY_SCOPE_AGENT);
        if (old == NBLK - 1) {                           // last block: all sums visible
            float loss = 0.f;
            #pragma unroll
            for (int e2 = 0; e2 < 8; ++e2) {
                float sp = __hip_atomic_load(ws + e2,     __ATOMIC_RELAXED, __HIP_MEMORY_SCOPE_AGENT);
                float sc = __hip_atomic_load(ws + 8 + e2, __ATOMIC_RELAXED, __HIP_MEMORY_SCOPE_AGENT);
                loss += (sp * (1.f / BB)) * (sc * (1.f / BB));
            }
            out[BB * 2 + BB * 8] = loss * (float)EE;
        }
    }
}

extern "C" void kernel_launch(void* const* d_in, const int* in_sizes, int n_in,
                              void* d_out, int out_size, void* d_ws, size_t ws_size,
                              hipStream_t stream) {
    (void)in_sizes; (void)n_in; (void)out_size; (void)ws_size;
    const float* x  = (const float*)d_in[0];
    const float* rw = (const float*)d_in[1];
    const float* ew = (const float*)d_in[2];
    const float* eb = (const float*)d_in[3];
    float* out = (float*)d_out;
    float* ws  = (float*)d_ws;                           // 17 floats: 8 sums + 8 counts + done-ctr

    hipMemsetAsync(ws, 0, 17 * sizeof(float), stream);   // graph-capture-safe on-stream memset
    moe_all<<<NBLK, 256, 0, stream>>>(x, rw, ew, eb, out, ws);
}

// Round 2
// 96.175 us; speedup vs baseline: 1.2174x; 1.2174x over previous
//
#include <hip/hip_runtime.h>

#define BB 2048
#define DD 4096
#define PP 64
#define KK 64
#define EE 8
#define C2 128
#define NBLK (BB / 2)   // 2 rows per block; 4 waves = 2 rows x 2 channel-halves

typedef __attribute__((ext_vector_type(8))) short short8;
typedef __attribute__((ext_vector_type(4))) float floatx4;

__device__ inline unsigned pack2_trunc(float lo, float hi) { // 2 bf16 (truncate) in 1 u32
    unsigned ul = __builtin_bit_cast(unsigned, lo);
    unsigned uh = __builtin_bit_cast(unsigned, hi);
    return (uh & 0xFFFF0000u) | (ul >> 16);
}

// One row per WAVE-PAIR: wave half 0 computes channels 0..63 (h0), half 1 computes 64..127 (h1).
// Both waves load the full x row + run the router redundantly (bit-identical => same e/gate; no sync
// needed until the final 2-logit softmax exchange). 1024 blocks -> 16 waves/CU (2x round-1 TLP).
// Loss: per-block partials (2 rows) via PLAIN stores to ws (no init, no atomics, no fence);
// tiny stage-2 kernel reduces 1024x16 floats.
__global__ __launch_bounds__(256, 4) void moe_main(
    const float* __restrict__ x, const float* __restrict__ rw,
    const float* __restrict__ ew, const float* __restrict__ eb,
    float* __restrict__ out, float* __restrict__ ws)
{
    __shared__ float red[2][9];                          // per-row d[0..7] + argmax (written by half-0 waves)
    __shared__ float sh_h[4];                            // per-wave channel-half sums
    const int lane = threadIdx.x & 63;
    const int w = threadIdx.x >> 6;
    const int half = w & 1;
    const int rowb = w >> 1;
    const int b = blockIdx.x * 2 + rowb;
    const int r = lane & 15, q = lane >> 4;
    const float* xb = x + (size_t)b * DD;

    // ---- load x in MFMA A-layout; fp32 col-sum partials; pack bf16 A-frags
    float ps[16];
    #pragma unroll
    for (int j = 0; j < 16; ++j) ps[j] = 0.f;
    short8 af[8];                                        // [mt*2+kb]
    #pragma unroll
    for (int mt = 0; mt < 4; ++mt) {
        #pragma unroll
        for (int kb = 0; kb < 2; ++kb) {
            const float* base = xb + (mt * 16 + r) * 64 + kb * 32 + q * 8;
            float4 v0 = *(const float4*)base;
            float4 v1 = *(const float4*)(base + 4);
            ps[kb*8+0] += v0.x; ps[kb*8+1] += v0.y; ps[kb*8+2] += v0.z; ps[kb*8+3] += v0.w;
            ps[kb*8+4] += v1.x; ps[kb*8+5] += v1.y; ps[kb*8+6] += v1.z; ps[kb*8+7] += v1.w;
            uint4 u;
            u.x = pack2_trunc(v0.x, v0.y); u.y = pack2_trunc(v0.z, v0.w);
            u.z = pack2_trunc(v1.x, v1.y); u.w = pack2_trunc(v1.z, v1.w);
            af[mt * 2 + kb] = __builtin_bit_cast(short8, u);
        }
    }

    // ---- router (fp32; strict first-max argmax matches np). Redundant across the wave pair:
    // identical instruction sequence on identical data -> bit-identical d[], e, gate.
    float d[8];
    #pragma unroll
    for (int e2 = 0; e2 < 8; ++e2) {
        const float* rwe = rw + e2 * KK;
        float4 a0 = *(const float4*)(rwe + q * 8);
        float4 a1 = *(const float4*)(rwe + q * 8 + 4);
        float4 b0 = *(const float4*)(rwe + 32 + q * 8);
        float4 b1 = *(const float4*)(rwe + 32 + q * 8 + 4);
        float t = ps[0]*a0.x + ps[1]*a0.y + ps[2]*a0.z + ps[3]*a0.w
                + ps[4]*a1.x + ps[5]*a1.y + ps[6]*a1.z + ps[7]*a1.w
                + ps[8]*b0.x + ps[9]*b0.y + ps[10]*b0.z + ps[11]*b0.w
                + ps[12]*b1.x + ps[13]*b1.y + ps[14]*b1.z + ps[15]*b1.w;
        t += __shfl_xor(t, 1);  t += __shfl_xor(t, 2);  t += __shfl_xor(t, 4);
        t += __shfl_xor(t, 8);  t += __shfl_xor(t, 16); t += __shfl_xor(t, 32);
        d[e2] = t;                                       // all lanes hold it
    }
    float gate = d[0]; int e = 0;
    #pragma unroll
    for (int e2 = 1; e2 < 8; ++e2)
        if (d[e2] > gate) { gate = d[e2]; e = e2; }

    if (lane == 0 && half == 0) {
        #pragma unroll
        for (int e2 = 0; e2 < 8; ++e2) red[rowb][e2] = d[e2];   // staged for in-block loss partial
        red[rowb][8] = (float)e;
        float on = (gate != 0.f) ? 1.f : 0.f;
        float4 o0 = make_float4(e==0?on:0.f, e==1?on:0.f, e==2?on:0.f, e==3?on:0.f);
        float4 o1 = make_float4(e==4?on:0.f, e==5?on:0.f, e==6?on:0.f, e==7?on:0.f);
        *(float4*)(out + BB * 2 + b * 8)     = o0;       // select0
        *(float4*)(out + BB * 2 + b * 8 + 4) = o1;
    }

    // ---- expert compute (this wave's channel half): inline fp32->bf16 B-frags, mfma, (z+bias)^3
    const float* we = ew + (size_t)e * (C2 * KK);
    float h = 0.f;
    #pragma unroll
    for (int ntl = 0; ntl < 4; ++ntl) {
        const int nt = half * 4 + ntl;
        float bs = eb[e * C2 + nt * 16 + r];             // c = nt*16 + (lane&15)
        const float* wr = we + (nt * 16 + r) * KK + q * 8;
        float4 w0 = *(const float4*)wr;
        float4 w1 = *(const float4*)(wr + 4);
        float4 w2 = *(const float4*)(wr + 32);
        float4 w3 = *(const float4*)(wr + 36);
        uint4 u0, u1;
        u0.x = pack2_trunc(w0.x, w0.y); u0.y = pack2_trunc(w0.z, w0.w);
        u0.z = pack2_trunc(w1.x, w1.y); u0.w = pack2_trunc(w1.z, w1.w);
        u1.x = pack2_trunc(w2.x, w2.y); u1.y = pack2_trunc(w2.z, w2.w);
        u1.z = pack2_trunc(w3.x, w3.y); u1.w = pack2_trunc(w3.z, w3.w);
        short8 bf0 = __builtin_bit_cast(short8, u0);
        short8 bf1 = __builtin_bit_cast(short8, u1);
        #pragma unroll
        for (int mt = 0; mt < 4; ++mt) {
            floatx4 a4 = (floatx4){0.f, 0.f, 0.f, 0.f};
            a4 = __builtin_amdgcn_mfma_f32_16x16x32_bf16(af[mt*2+0], bf0, a4, 0, 0, 0);
            a4 = __builtin_amdgcn_mfma_f32_16x16x32_bf16(af[mt*2+1], bf1, a4, 0, 0, 0);
            #pragma unroll
            for (int i = 0; i < 4; ++i) {
                float z = a4[i] + bs;
                h = fmaf(z * z, z, h);
            }
        }
    }
    #pragma unroll
    for (int off = 1; off < 64; off <<= 1)
        h += __shfl_xor(h, off);

    if (lane == 0) sh_h[w] = h;
    __syncthreads();

    if (half == 0 && lane == 0) {
        float l0 = gate * sh_h[w], l1 = gate * sh_h[w + 1];
        float m = fmaxf(l0, l1);
        float e0 = __expf(l0 - m), e1 = __expf(l1 - m);
        float inv = 1.f / (e0 + e1);
        float2 o; o.x = e0 * inv; o.y = e1 * inv;
        *(float2*)(out + b * 2) = o;
    }

    // ---- loss partial for this block's 2 rows: plain stores, distinct addresses, no init needed
    if (threadIdx.x < 8) {
        const int t = threadIdx.x;
        float sp = red[0][t] + red[1][t];
        float sc = ((red[0][8] == (float)t) ? 1.f : 0.f) + ((red[1][8] == (float)t) ? 1.f : 0.f);
        ws[blockIdx.x * 16 + t]     = sp;
        ws[blockIdx.x * 16 + 8 + t] = sc;
    }
}

// Stage 2: reduce 1024 block-partials (16 floats each) -> loss. One block, ~64 KB read.
__global__ __launch_bounds__(256) void loss2(
    const float* __restrict__ ws, float* __restrict__ out)
{
    __shared__ float red[4][16];
    const int t = threadIdx.x;
    const int w = t >> 6, lane = t & 63;

    float p[8] = {0,0,0,0,0,0,0,0};
    float c[8] = {0,0,0,0,0,0,0,0};
    #pragma unroll
    for (int it = 0; it < NBLK / 256; ++it) {            // 4 iterations
        const float4* row = (const float4*)(ws + (size_t)(it * 256 + t) * 16);
        float4 r0 = row[0], r1 = row[1], r2 = row[2], r3 = row[3];
        p[0] += r0.x; p[1] += r0.y; p[2] += r0.z; p[3] += r0.w;
        p[4] += r1.x; p[5] += r1.y; p[6] += r1.z; p[7] += r1.w;
        c[0] += r2.x; c[1] += r2.y; c[2] += r2.z; c[3] += r2.w;
        c[4] += r3.x; c[5] += r3.y; c[6] += r3.z; c[7] += r3.w;
    }
    #pragma unroll
    for (int off = 32; off > 0; off >>= 1) {
        #pragma unroll
        for (int e2 = 0; e2 < 8; ++e2) {
            p[e2] += __shfl_xor(p[e2], off);
            c[e2] += __shfl_xor(c[e2], off);
        }
    }
    if (lane == 0) {
        #pragma unroll
        for (int e2 = 0; e2 < 8; ++e2) { red[w][e2] = p[e2]; red[w][8 + e2] = c[e2]; }
    }
    __syncthreads();
    if (t == 0) {
        float loss = 0.f;
        #pragma unroll
        for (int e2 = 0; e2 < 8; ++e2) {
            float sp = red[0][e2] + red[1][e2] + red[2][e2] + red[3][e2];
            float sc = red[0][8 + e2] + red[1][8 + e2] + red[2][8 + e2] + red[3][8 + e2];
            loss += (sp * (1.f / BB)) * (sc * (1.f / BB));
        }
        out[BB * 2 + BB * 8] = loss * (float)EE;
    }
}

extern "C" void kernel_launch(void* const* d_in, const int* in_sizes, int n_in,
                              void* d_out, int out_size, void* d_ws, size_t ws_size,
                              hipStream_t stream) {
    (void)in_sizes; (void)n_in; (void)out_size; (void)ws_size;
    const float* x  = (const float*)d_in[0];
    const float* rw = (const float*)d_in[1];
    const float* ew = (const float*)d_in[2];
    const float* eb = (const float*)d_in[3];
    float* out = (float*)d_out;
    float* ws  = (float*)d_ws;                           // 1024*16 floats of block partials (no init)

    moe_main<<<NBLK, 256, 0, stream>>>(x, rw, ew, eb, out, ws);
    loss2<<<1, 256, 0, stream>>>(ws, out);
}